// Round 1
// baseline (731.190 us; speedup 1.0000x reference)
//
#include <hip/hip_runtime.h>
#include <math.h>

// custom_att_1d: per-token hypernet attention, N=131072 tokens, 64 channels.
// Strategy (round 1, fp32 baseline):
//  - thread-per-token; kv[64] in VGPRs; all weight reads wave-uniform -> s_load
//    (scalar path), so inner loops are pure v_fma_f32 (VGPR x SGPR) at 2cyc.
//  - q = T@kv computed WITHOUT materializing T:
//      q[i] = sum_p query'[p] * (T_W[p, i*64: i*64+64] . kv),  query'[7]=1 for T_b.
//  - weights pre-transposed into d_ws so each output-channel dot is a contiguous
//    64-dword row (s_load_dwordx16-able).
//  - per-thread 64-float relay buffer in LDS, stride 65 -> bank (lane+i)%32,
//    conflict-free. Outer channel loops dynamic -> small code, L1I-resident.
// Compute-bound: ~13 GFLOP fp32 -> 83us floor at 157 TF vector.

#define NTOK  131072
#define TPB   128
#define EPSN  1e-8f

// float offsets inside ws
#define WS_KEYWT 0
#define WS_VALWT 4096
#define WS_D1WT  8192
#define WS_D2WT  12288
#define WS_D3WT  14336

__global__ __launch_bounds__(256)
void xpose_k(const float* __restrict__ keyW, const float* __restrict__ valW,
             const float* __restrict__ d1W, const float* __restrict__ d2W,
             const float* __restrict__ d3W, float* __restrict__ ws)
{
    int idx = blockIdx.x * 256 + threadIdx.x;
    if (idx < 4096) {
        int i = idx >> 6, j = idx & 63;
        ws[WS_KEYWT + idx] = keyW[j * 64 + i];
    } else if (idx < 8192) {
        int r = idx - 4096, i = r >> 6, j = r & 63;
        ws[WS_VALWT + r] = valW[j * 64 + i];
    } else if (idx < 12288) {
        int r = idx - 8192, i = r >> 6, j = r & 63;
        ws[WS_D1WT + r] = d1W[j * 64 + i];
    } else if (idx < 14336) {
        int r = idx - 12288, i = r >> 6, j = r & 63;   // d2WT: [32][64]
        ws[WS_D2WT + r] = d2W[j * 32 + i];
    } else if (idx < 16384) {
        int r = idx - 14336, i = r >> 5, j = r & 31;   // d3WT: [64][32]
        ws[WS_D3WT + r] = d3W[j * 64 + i];
    }
}

__global__ __launch_bounds__(TPB, 2)
void fused_main(const float* __restrict__ kv_in, const float* __restrict__ q_in,
                const float* __restrict__ keyB, const float* __restrict__ valB,
                const float* __restrict__ TW,   const float* __restrict__ TB,
                const float* __restrict__ d1B,  const float* __restrict__ d2B,
                const float* __restrict__ d3B,  const float* __restrict__ scale_p,
                const float* __restrict__ ws,   float* __restrict__ out)
{
    __shared__ float Bbuf[TPB * 65];
    const int  tid = threadIdx.x;
    const long t   = (long)blockIdx.x * TPB + tid;
    float* __restrict__ Bl = &Bbuf[tid * 65];   // bank = (tid + i) % 32: conflict-free

    const float* __restrict__ keyWT = ws + WS_KEYWT;
    const float* __restrict__ valWT = ws + WS_VALWT;
    const float* __restrict__ d1WT  = ws + WS_D1WT;
    const float* __restrict__ d2WT  = ws + WS_D2WT;
    const float* __restrict__ d3WT  = ws + WS_D3WT;

    // ---- per-token inputs
    float kv[64];
    {
        const float4* p = (const float4*)(kv_in + t * 64);
        #pragma unroll
        for (int j4 = 0; j4 < 16; ++j4) {
            float4 f = p[j4];
            kv[4 * j4 + 0] = f.x; kv[4 * j4 + 1] = f.y;
            kv[4 * j4 + 2] = f.z; kv[4 * j4 + 3] = f.w;
        }
    }
    float qr[8];
    {
        const float* p = q_in + t * 7;
        #pragma unroll
        for (int c = 0; c < 7; ++c) qr[c] = p[c];
        qr[7] = 1.0f;   // bias slot for T_b
    }
    const float sc = scale_p[0];

    // ---- P1: v = (kv @ value_W + b) * scale  -> Bl, track running max
    float m = -3.4e38f;
    for (int i = 0; i < 64; ++i) {
        const float* __restrict__ w = valWT + (i << 6);
        float acc = valB[i];
        #pragma unroll
        for (int j = 0; j < 64; ++j) acc = fmaf(kv[j], w[j], acc);
        acc *= sc;
        m = fmaxf(m, acc);
        Bl[i] = acc;
    }

    // ---- P2: exp & sum (softmax numerators stay in Bl)
    float s = 0.f;
    for (int i = 0; i < 64; ++i) {
        float e = __expf(Bl[i] - m);
        s += e;
        Bl[i] = e;
    }

    // ---- P3: per channel i: k_i, q_i (8 dots), att_i = q_i*k_i
    //          Bl[i] <- att_i * exp_i ; norm2 += att_i^2
    float norm2 = 0.f;
    for (int i = 0; i < 64; ++i) {
        const float* __restrict__ wk = keyWT + (i << 6);
        float kacc = keyB[i];
        #pragma unroll
        for (int j = 0; j < 64; ++j) kacc = fmaf(kv[j], wk[j], kacc);

        float dots[8];
        #pragma unroll
        for (int p = 0; p < 8; ++p) {
            const float* __restrict__ wt = (p == 7) ? (TB + (i << 6))
                                                    : (TW + p * 4096 + (i << 6));
            float d = 0.f;
            #pragma unroll
            for (int j = 0; j < 64; ++j) d = fmaf(kv[j], wt[j], d);
            dots[p] = d;
        }
        float q = dots[7];
        #pragma unroll
        for (int p = 0; p < 7; ++p) q = fmaf(qr[p], dots[p], q);

        float att = q * kacc;
        norm2 = fmaf(att, att, norm2);
        Bl[i] = att * Bl[i];
    }
    const float rnorm = 1.0f / fmaxf(sqrtf(norm2), EPSN);
    const float cfac  = rnorm / s;   // folds 1/softmax_sum and 1/||att||

    // ---- P4: pull x = att_norm * v_soft into registers
    float y[64];
    #pragma unroll
    for (int j = 0; j < 64; ++j) y[j] = Bl[j] * cfac;

    // ---- P5: h1 = relu(x @ d1 + b1)  (relay via LDS into fixed regs)
    for (int i = 0; i < 64; ++i) {
        const float* __restrict__ w = d1WT + (i << 6);
        float acc = d1B[i];
        #pragma unroll
        for (int j = 0; j < 64; ++j) acc = fmaf(y[j], w[j], acc);
        Bl[i] = fmaxf(acc, 0.f);
    }
    float h1[64];
    #pragma unroll
    for (int j = 0; j < 64; ++j) h1[j] = Bl[j];

    // ---- P6: h2 = relu(h1 @ d2 + b2)
    for (int i = 0; i < 32; ++i) {
        const float* __restrict__ w = d2WT + (i << 6);
        float acc = d2B[i];
        #pragma unroll
        for (int j = 0; j < 64; ++j) acc = fmaf(h1[j], w[j], acc);
        Bl[i] = fmaxf(acc, 0.f);
    }
    float h2[32];
    #pragma unroll
    for (int j = 0; j < 32; ++j) h2[j] = Bl[j];

    // ---- P7: out = h2 @ d3 + b3, float4 stores
    float* __restrict__ op = out + t * 64;
    for (int ib = 0; ib < 16; ++ib) {
        float o[4];
        #pragma unroll
        for (int c = 0; c < 4; ++c) {
            const int i = 4 * ib + c;
            const float* __restrict__ w = d3WT + (i << 5);
            float acc = d3B[i];
            #pragma unroll
            for (int j = 0; j < 32; ++j) acc = fmaf(h2[j], w[j], acc);
            o[c] = acc;
        }
        ((float4*)op)[ib] = make_float4(o[0], o[1], o[2], o[3]);
    }
}

extern "C" void kernel_launch(void* const* d_in, const int* in_sizes, int n_in,
                              void* d_out, int out_size, void* d_ws, size_t ws_size,
                              hipStream_t stream) {
    const float* kv_in = (const float*)d_in[0];
    const float* q_in  = (const float*)d_in[1];
    const float* keyW  = (const float*)d_in[2];
    const float* keyB  = (const float*)d_in[3];
    const float* valW  = (const float*)d_in[4];
    const float* valB  = (const float*)d_in[5];
    const float* TW    = (const float*)d_in[6];
    const float* TB    = (const float*)d_in[7];
    const float* d1W   = (const float*)d_in[8];
    const float* d1B   = (const float*)d_in[9];
    const float* d2W   = (const float*)d_in[10];
    const float* d2B   = (const float*)d_in[11];
    const float* d3W   = (const float*)d_in[12];
    const float* d3B   = (const float*)d_in[13];
    const float* scale = (const float*)d_in[14];
    float* ws   = (float*)d_ws;
    float* outp = (float*)d_out;

    xpose_k<<<64, 256, 0, stream>>>(keyW, valW, d1W, d2W, d3W, ws);
    fused_main<<<NTOK / TPB, TPB, 0, stream>>>(kv_in, q_in, keyB, valB, TW, TB,
                                               d1B, d2B, d3B, scale, ws, outp);
}

// Round 2
// 223.277 us; speedup vs baseline: 3.2748x; 3.2748x over previous
//
#include <hip/hip_runtime.h>
#include <math.h>

typedef unsigned short ushort_t;
typedef __attribute__((ext_vector_type(8))) short bf16x8;
typedef __attribute__((ext_vector_type(4))) float f32x4;

#define NTOK 131072
#define MT   128      // tokens per block
#define TPB  256      // 4 waves

// ws layout (ushort elems): hi half then lo half
#define OFF_KEY 0
#define OFF_VAL 4096
#define OFF_T   8192      // 8 matrices of 4096 (p=0..6 from T_W, p=7 = T_b)
#define OFF_D1  40960
#define OFF_D2  45056     // [32][64]
#define OFF_D3  47104     // [64][32]
#define WTOT    49152

__device__ __forceinline__ ushort_t f2bf(float f) {
    unsigned u = __builtin_bit_cast(unsigned, f);
    unsigned r = (u + 0x7fffu + ((u >> 16) & 1u)) >> 16;   // RNE
    return (ushort_t)r;
}
__device__ __forceinline__ float bf2f(ushort_t h) {
    return __builtin_bit_cast(float, (unsigned)h << 16);
}

__device__ __forceinline__ f32x4 mfma16(bf16x8 a, bf16x8 b, f32x4 c) {
    return __builtin_amdgcn_mfma_f32_16x16x32_bf16(a, b, c, 0, 0, 0);
}

// ---------------- prep: split+transpose all weights into ws (bf16 hi/lo) ----
__global__ __launch_bounds__(256)
void prep_w(const float* __restrict__ keyW, const float* __restrict__ valW,
            const float* __restrict__ TW,   const float* __restrict__ TB,
            const float* __restrict__ d1W,  const float* __restrict__ d2W,
            const float* __restrict__ d3W,
            ushort_t* __restrict__ whi, ushort_t* __restrict__ wlo)
{
    int idx = blockIdx.x * 256 + threadIdx.x;
    if (idx >= WTOT) return;
    float src;
    if (idx < OFF_VAL) {                      // key: BT[n][j] = keyW[j][n]
        int r = idx - OFF_KEY, n = r >> 6, j = r & 63;
        src = keyW[j * 64 + n];
    } else if (idx < OFF_T) {                 // val
        int r = idx - OFF_VAL, n = r >> 6, j = r & 63;
        src = valW[j * 64 + n];
    } else if (idx < OFF_D1) {                // T_p: BT[n][j] = TW[p][n*64+j]
        int r = idx - OFF_T, p = r >> 12, q = r & 4095;
        src = (p < 7) ? TW[p * 4096 + q] : TB[q];
    } else if (idx < OFF_D2) {                // d1
        int r = idx - OFF_D1, n = r >> 6, j = r & 63;
        src = d1W[j * 64 + n];
    } else if (idx < OFF_D3) {                // d2: BT[n<32][j<64] = d2W[j*32+n]
        int r = idx - OFF_D2, n = r >> 6, j = r & 63;
        src = d2W[j * 32 + n];
    } else {                                  // d3: BT[n<64][j<32] = d3W[j*64+n]
        int r = idx - OFF_D3, n = r >> 5, j = r & 31;
        src = d3W[j * 64 + n];
    }
    ushort_t h = f2bf(src);
    whi[idx] = h;
    wlo[idx] = f2bf(src - bf2f(h));
}

// ---------------- main fused kernel ----------------------------------------
template<int NC>
__device__ __forceinline__ void gemm64(const ushort_t* __restrict__ bh_base,
                                       const ushort_t* __restrict__ bl_base,
                                       int l15, int quad,
                                       const bf16x8 ahi[2][2], const bf16x8 alo[2][2],
                                       f32x4 acc[2][4])
{
#pragma unroll
    for (int c = 0; c < NC; ++c) {
        const ushort_t* ph = bh_base + (16 * c + l15) * 64 + quad * 8;
        const ushort_t* pl = bl_base + (16 * c + l15) * 64 + quad * 8;
        bf16x8 bh0 = *(const bf16x8*)(ph);
        bf16x8 bh1 = *(const bf16x8*)(ph + 32);
        bf16x8 bl0 = *(const bf16x8*)(pl);
        bf16x8 bl1 = *(const bf16x8*)(pl + 32);
#pragma unroll
        for (int rt = 0; rt < 2; ++rt) {
            f32x4 a = acc[rt][c];
            a = mfma16(alo[rt][0], bh0, a);
            a = mfma16(ahi[rt][0], bl0, a);
            a = mfma16(ahi[rt][0], bh0, a);
            a = mfma16(alo[rt][1], bh1, a);
            a = mfma16(ahi[rt][1], bl1, a);
            a = mfma16(ahi[rt][1], bh1, a);
            acc[rt][c] = a;
        }
    }
}

__global__ __launch_bounds__(TPB, 2)
void fused_mfma(const float* __restrict__ kv_in, const float* __restrict__ q_in,
                const float* __restrict__ keyB,  const float* __restrict__ valB,
                const float* __restrict__ d1B,   const float* __restrict__ d2B,
                const float* __restrict__ d3B,   const float* __restrict__ scale_p,
                const ushort_t* __restrict__ whi, const ushort_t* __restrict__ wlo,
                float* __restrict__ out)
{
    __shared__ ushort_t Ahi[MT][72];   // 18432 B  (pad 8 -> 2-way-free banks)
    __shared__ ushort_t Alo[MT][72];   // 18432 B
    __shared__ float    Qt[8][MT];     // 4096 B  (query transposed, q'[7]=1)

    const int tid  = threadIdx.x;
    const int wv   = tid >> 6, lane = tid & 63;
    const int quad = lane >> 4, l15 = lane & 15;
    const int RB   = wv * 32;                    // wave's row base (owns 32 rows)
    const long t0  = (long)blockIdx.x * MT;

    // ---- stage KV tile -> split bf16 hi/lo in LDS (wave-private rows) ----
    {
        int r = tid >> 1, hc = (tid & 1) * 32;
        const float4* p4 = (const float4*)(kv_in + (t0 + r) * 64 + hc);
#pragma unroll
        for (int b = 0; b < 4; ++b) {
            float4 f0 = p4[2 * b], f1 = p4[2 * b + 1];
            float fs[8] = {f0.x, f0.y, f0.z, f0.w, f1.x, f1.y, f1.z, f1.w};
            bf16x8 hv, lv;
#pragma unroll
            for (int j = 0; j < 8; ++j) {
                ushort_t h = f2bf(fs[j]);
                hv[j] = (short)h;
                lv[j] = (short)f2bf(fs[j] - bf2f(h));
            }
            *(bf16x8*)&Ahi[r][hc + 8 * b] = hv;
            *(bf16x8*)&Alo[r][hc + 8 * b] = lv;
        }
    }
    if (tid < MT) {
        const float* qp = q_in + (t0 + tid) * 7;
#pragma unroll
        for (int p = 0; p < 7; ++p) Qt[p][tid] = qp[p];
        Qt[7][tid] = 1.0f;
    }
    __syncthreads();

    // ---- A-fragments (kv) ----
    bf16x8 ahi[2][2], alo[2][2];
#pragma unroll
    for (int rt = 0; rt < 2; ++rt)
#pragma unroll
        for (int ks = 0; ks < 2; ++ks) {
            ahi[rt][ks] = *(const bf16x8*)&Ahi[RB + 16 * rt + l15][ks * 32 + quad * 8];
            alo[rt][ks] = *(const bf16x8*)&Alo[RB + 16 * rt + l15][ks * 32 + quad * 8];
        }

    // ---- T stage: q = sum_p q'_p * (KV @ T_p^T) ----
    f32x4 qacc[2][4] = {};
#pragma unroll 1
    for (int p = 0; p < 8; ++p) {
        f32x4 tmp[2][4] = {};
        gemm64<4>(whi + OFF_T + p * 4096, wlo + OFF_T + p * 4096, l15, quad, ahi, alo, tmp);
        f32x4 qp0 = *(const f32x4*)&Qt[p][RB + quad * 4];
        f32x4 qp1 = *(const f32x4*)&Qt[p][RB + 16 + quad * 4];
#pragma unroll
        for (int c = 0; c < 4; ++c)
#pragma unroll
            for (int e = 0; e < 4; ++e) {
                qacc[0][c][e] = fmaf(qp0[e], tmp[0][c][e], qacc[0][c][e]);
                qacc[1][c][e] = fmaf(qp1[e], tmp[1][c][e], qacc[1][c][e]);
            }
    }

    // ---- k, v stages ----
    f32x4 kacc[2][4] = {}, vacc[2][4] = {};
    gemm64<4>(whi + OFF_KEY, wlo + OFF_KEY, l15, quad, ahi, alo, kacc);
    gemm64<4>(whi + OFF_VAL, wlo + OFF_VAL, l15, quad, ahi, alo, vacc);

    // ---- elementwise: softmax(v*sc), att=q*k, L2-normalize, x=att*v ----
    const float sc = scale_p[0];
    float kb[4], vb[4];
#pragma unroll
    for (int c = 0; c < 4; ++c) { kb[c] = keyB[16 * c + l15]; vb[c] = valB[16 * c + l15]; }

    f32x4 xv[2][4];
#pragma unroll
    for (int rt = 0; rt < 2; ++rt) {
        f32x4 sv[4], mx;
#pragma unroll
        for (int e = 0; e < 4; ++e) mx[e] = -3.4e38f;
#pragma unroll
        for (int c = 0; c < 4; ++c) {
            sv[c] = (vacc[rt][c] + vb[c]) * sc;
#pragma unroll
            for (int e = 0; e < 4; ++e) mx[e] = fmaxf(mx[e], sv[c][e]);
        }
#pragma unroll
        for (int m = 1; m < 16; m <<= 1)
#pragma unroll
            for (int e = 0; e < 4; ++e) mx[e] = fmaxf(mx[e], __shfl_xor(mx[e], m, 64));
        f32x4 se = {};
#pragma unroll
        for (int c = 0; c < 4; ++c) {
#pragma unroll
            for (int e = 0; e < 4; ++e) sv[c][e] = __expf(sv[c][e] - mx[e]);
            se += sv[c];
        }
#pragma unroll
        for (int m = 1; m < 16; m <<= 1)
#pragma unroll
            for (int e = 0; e < 4; ++e) se[e] += __shfl_xor(se[e], m, 64);
        f32x4 nr = {};
        f32x4 at[4];
#pragma unroll
        for (int c = 0; c < 4; ++c) {
            at[c] = qacc[rt][c] * (kacc[rt][c] + kb[c]);
            nr += at[c] * at[c];
        }
#pragma unroll
        for (int m = 1; m < 16; m <<= 1)
#pragma unroll
            for (int e = 0; e < 4; ++e) nr[e] += __shfl_xor(nr[e], m, 64);
        f32x4 fac;
#pragma unroll
        for (int e = 0; e < 4; ++e)
            fac[e] = 1.0f / (fmaxf(sqrtf(nr[e]), 1e-8f) * se[e]);
#pragma unroll
        for (int c = 0; c < 4; ++c) xv[rt][c] = at[c] * sv[c] * fac;
    }

    // ---- relay x -> LDS (bf16 hi/lo, wave-private rows), d1 GEMM ----
    __syncthreads();
#pragma unroll
    for (int rt = 0; rt < 2; ++rt)
#pragma unroll
        for (int c = 0; c < 4; ++c)
#pragma unroll
            for (int e = 0; e < 4; ++e) {
                int row = RB + 16 * rt + quad * 4 + e, col = 16 * c + l15;
                float f = xv[rt][c][e];
                ushort_t h = f2bf(f);
                Ahi[row][col] = h;
                Alo[row][col] = f2bf(f - bf2f(h));
            }
    __syncthreads();
#pragma unroll
    for (int rt = 0; rt < 2; ++rt)
#pragma unroll
        for (int ks = 0; ks < 2; ++ks) {
            ahi[rt][ks] = *(const bf16x8*)&Ahi[RB + 16 * rt + l15][ks * 32 + quad * 8];
            alo[rt][ks] = *(const bf16x8*)&Alo[RB + 16 * rt + l15][ks * 32 + quad * 8];
        }
    f32x4 h1a[2][4] = {};
    gemm64<4>(whi + OFF_D1, wlo + OFF_D1, l15, quad, ahi, alo, h1a);
    {
        float b1[4];
#pragma unroll
        for (int c = 0; c < 4; ++c) b1[c] = d1B[16 * c + l15];
#pragma unroll
        for (int rt = 0; rt < 2; ++rt)
#pragma unroll
            for (int c = 0; c < 4; ++c)
#pragma unroll
                for (int e = 0; e < 4; ++e) h1a[rt][c][e] = fmaxf(h1a[rt][c][e] + b1[c], 0.f);
    }

    // ---- relay h1, d2 GEMM (out cols 32) ----
    __syncthreads();
#pragma unroll
    for (int rt = 0; rt < 2; ++rt)
#pragma unroll
        for (int c = 0; c < 4; ++c)
#pragma unroll
            for (int e = 0; e < 4; ++e) {
                int row = RB + 16 * rt + quad * 4 + e, col = 16 * c + l15;
                float f = h1a[rt][c][e];
                ushort_t h = f2bf(f);
                Ahi[row][col] = h;
                Alo[row][col] = f2bf(f - bf2f(h));
            }
    __syncthreads();
#pragma unroll
    for (int rt = 0; rt < 2; ++rt)
#pragma unroll
        for (int ks = 0; ks < 2; ++ks) {
            ahi[rt][ks] = *(const bf16x8*)&Ahi[RB + 16 * rt + l15][ks * 32 + quad * 8];
            alo[rt][ks] = *(const bf16x8*)&Alo[RB + 16 * rt + l15][ks * 32 + quad * 8];
        }
    f32x4 h2a[2][4] = {};
    gemm64<2>(whi + OFF_D2, wlo + OFF_D2, l15, quad, ahi, alo, h2a);
    {
        float b2[2];
#pragma unroll
        for (int c = 0; c < 2; ++c) b2[c] = d2B[16 * c + l15];
#pragma unroll
        for (int rt = 0; rt < 2; ++rt)
#pragma unroll
            for (int c = 0; c < 2; ++c)
#pragma unroll
                for (int e = 0; e < 4; ++e) h2a[rt][c][e] = fmaxf(h2a[rt][c][e] + b2[c], 0.f);
    }

    // ---- relay h2 (cols 0..31), d3 GEMM (K=32) ----
    __syncthreads();
#pragma unroll
    for (int rt = 0; rt < 2; ++rt)
#pragma unroll
        for (int c = 0; c < 2; ++c)
#pragma unroll
            for (int e = 0; e < 4; ++e) {
                int row = RB + 16 * rt + quad * 4 + e, col = 16 * c + l15;
                float f = h2a[rt][c][e];
                ushort_t h = f2bf(f);
                Ahi[row][col] = h;
                Alo[row][col] = f2bf(f - bf2f(h));
            }
    __syncthreads();
    bf16x8 a3h[2], a3l[2];
#pragma unroll
    for (int rt = 0; rt < 2; ++rt) {
        a3h[rt] = *(const bf16x8*)&Ahi[RB + 16 * rt + l15][quad * 8];
        a3l[rt] = *(const bf16x8*)&Alo[RB + 16 * rt + l15][quad * 8];
    }
    f32x4 oa[2][4] = {};
#pragma unroll
    for (int c = 0; c < 4; ++c) {
        const ushort_t* ph = whi + OFF_D3 + (16 * c + l15) * 32 + quad * 8;
        const ushort_t* pl = wlo + OFF_D3 + (16 * c + l15) * 32 + quad * 8;
        bf16x8 bh = *(const bf16x8*)ph;
        bf16x8 bl = *(const bf16x8*)pl;
#pragma unroll
        for (int rt = 0; rt < 2; ++rt) {
            f32x4 a = oa[rt][c];
            a = mfma16(a3l[rt], bh, a);
            a = mfma16(a3h[rt], bl, a);
            a = mfma16(a3h[rt], bh, a);
            oa[rt][c] = a;
        }
    }

    // ---- epilogue: + d3_b, store ----
    float b3[4];
#pragma unroll
    for (int c = 0; c < 4; ++c) b3[c] = d3B[16 * c + l15];
#pragma unroll
    for (int rt = 0; rt < 2; ++rt)
#pragma unroll
        for (int c = 0; c < 4; ++c)
#pragma unroll
            for (int e = 0; e < 4; ++e) {
                long row = t0 + RB + 16 * rt + quad * 4 + e;
                out[row * 64 + 16 * c + l15] = oa[rt][c][e] + b3[c];
            }
}

extern "C" void kernel_launch(void* const* d_in, const int* in_sizes, int n_in,
                              void* d_out, int out_size, void* d_ws, size_t ws_size,
                              hipStream_t stream) {
    (void)in_sizes; (void)n_in; (void)out_size; (void)ws_size;
    const float* kv_in = (const float*)d_in[0];
    const float* q_in  = (const float*)d_in[1];
    const float* keyW  = (const float*)d_in[2];
    const float* keyB  = (const float*)d_in[3];
    const float* valW  = (const float*)d_in[4];
    const float* valB  = (const float*)d_in[5];
    const float* TW    = (const float*)d_in[6];
    const float* TB    = (const float*)d_in[7];
    const float* d1W   = (const float*)d_in[8];
    const float* d1B   = (const float*)d_in[9];
    const float* d2W   = (const float*)d_in[10];
    const float* d2B   = (const float*)d_in[11];
    const float* d3W   = (const float*)d_in[12];
    const float* d3B   = (const float*)d_in[13];
    const float* scale = (const float*)d_in[14];
    ushort_t* whi = (ushort_t*)d_ws;
    ushort_t* wlo = whi + WTOT;
    float* outp = (float*)d_out;

    prep_w<<<(WTOT + 255) / 256, 256, 0, stream>>>(keyW, valW, TW, TB, d1W, d2W, d3W, whi, wlo);
    fused_mfma<<<NTOK / MT, TPB, 0, stream>>>(kv_in, q_in, keyB, valB,
                                              d1B, d2B, d3B, scale, whi, wlo, outp);
}